// Round 5
// baseline (493.373 us; speedup 1.0000x reference)
//
#include <hip/hip_runtime.h>
#include <hip/hip_bf16.h>

#define NNODES 100000
#define NEDGES 1600000
#define ALPHA  0.2f
#define EPSV   1e-9f

typedef __bf16 bf16x8 __attribute__((ext_vector_type(8)));
typedef float  f32x4  __attribute__((ext_vector_type(4)));
typedef unsigned short u16x8 __attribute__((ext_vector_type(8)));

// manual RNE f32 -> bf16 bits
static __device__ inline unsigned short f2bf(float f) {
    unsigned int u = __float_as_uint(f);
    unsigned int r = u + 0x7fff + ((u >> 16) & 1);
    return (unsigned short)(r >> 16);
}
static __device__ inline float bf2f(unsigned short v) {
    return __uint_as_float((unsigned int)v << 16);
}

// ---------------- zero counts + cast/transpose W, one launch ----------------
__global__ void k_zero_prep(int* __restrict__ counts,
                            const float* __restrict__ W,
                            unsigned short* __restrict__ Wt) {
    const int i = blockIdx.x * 256 + threadIdx.x;
    if (i < NNODES) counts[i] = 0;
    if (i < 65536) {                       // Wt[n][k] = bf16(W[k][n])
        const int n = i >> 8, k = i & 255;
        Wt[i] = f2bf(W[k * 256 + n]);
    }
}

// ---------------- degree histogram ----------------
__global__ void k_count(const int* __restrict__ src, int* __restrict__ counts) {
    const int e = blockIdx.x * 256 + threadIdx.x;
    if (e < NEDGES) atomicAdd(&counts[src[e]], 1);
}

// ---------------- bf16 MFMA GEMM: Wh[bf16] = h @ W (unchanged from R3) ----------------
#define BM 128
#define BK 32
#define LSTRIDE 40
__global__ __launch_bounds__(256, 2) void k_gemm(const float* __restrict__ h,
                                                 const unsigned short* __restrict__ Wt,
                                                 unsigned short* __restrict__ Wh) {
    __shared__ __align__(16) unsigned short As[BM * LSTRIDE];
    __shared__ __align__(16) unsigned short Bs[256 * LSTRIDE];
    const int tid  = threadIdx.x;
    const int m0   = blockIdx.x * BM;
    const int wave = tid >> 6;
    const int lane = tid & 63;
    const int wm = (wave & 1) * 64;
    const int wn = (wave >> 1) * 128;
    const int fm = lane & 15;
    const int fq = lane >> 4;
    const int fk = fq * 8;

    f32x4 acc[4][8];
    const f32x4 z = {0.f, 0.f, 0.f, 0.f};
#pragma unroll
    for (int i = 0; i < 4; ++i)
#pragma unroll
        for (int j = 0; j < 8; ++j) acc[i][j] = z;

    const int arow = tid >> 1;
    const int acol = (tid & 1) * 16;
    const bool arow_ok = (m0 + arow) < NNODES;
    const float* hrow = h + (size_t)(m0 + arow) * 256 + acol;

    for (int kc = 0; kc < 256; kc += BK) {
        float4 a0, a1, a2, a3;
        if (arow_ok) {
            a0 = *(const float4*)(hrow + kc + 0);
            a1 = *(const float4*)(hrow + kc + 4);
            a2 = *(const float4*)(hrow + kc + 8);
            a3 = *(const float4*)(hrow + kc + 12);
        } else {
            a0 = a1 = a2 = a3 = make_float4(0.f, 0.f, 0.f, 0.f);
        }
        u16x8 bv[4];
#pragma unroll
        for (int q = 0; q < 4; ++q) {
            const int c = tid + 256 * q;
            const int n = c >> 2, koff = (c & 3) * 8;
            bv[q] = *(const u16x8*)(Wt + n * 256 + kc + koff);
        }
        __syncthreads();
        u16x8 p0, p1;
        p0[0]=f2bf(a0.x); p0[1]=f2bf(a0.y); p0[2]=f2bf(a0.z); p0[3]=f2bf(a0.w);
        p0[4]=f2bf(a1.x); p0[5]=f2bf(a1.y); p0[6]=f2bf(a1.z); p0[7]=f2bf(a1.w);
        p1[0]=f2bf(a2.x); p1[1]=f2bf(a2.y); p1[2]=f2bf(a2.z); p1[3]=f2bf(a2.w);
        p1[4]=f2bf(a3.x); p1[5]=f2bf(a3.y); p1[6]=f2bf(a3.z); p1[7]=f2bf(a3.w);
        *(u16x8*)&As[arow * LSTRIDE + acol]     = p0;
        *(u16x8*)&As[arow * LSTRIDE + acol + 8] = p1;
#pragma unroll
        for (int q = 0; q < 4; ++q) {
            const int c = tid + 256 * q;
            const int n = c >> 2, koff = (c & 3) * 8;
            *(u16x8*)&Bs[n * LSTRIDE + koff] = bv[q];
        }
        __syncthreads();
        bf16x8 af[4], bfr[8];
#pragma unroll
        for (int i = 0; i < 4; ++i)
            af[i] = __builtin_bit_cast(bf16x8,
                *(const u16x8*)&As[(wm + 16 * i + fm) * LSTRIDE + fk]);
#pragma unroll
        for (int j = 0; j < 8; ++j)
            bfr[j] = __builtin_bit_cast(bf16x8,
                *(const u16x8*)&Bs[(wn + 16 * j + fm) * LSTRIDE + fk]);
#pragma unroll
        for (int i = 0; i < 4; ++i)
#pragma unroll
            for (int j = 0; j < 8; ++j)
                acc[i][j] = __builtin_amdgcn_mfma_f32_16x16x32_bf16(af[i], bfr[j], acc[i][j], 0, 0, 0);
    }
#pragma unroll
    for (int i = 0; i < 4; ++i) {
#pragma unroll
        for (int r = 0; r < 4; ++r) {
            const int grow = m0 + wm + 16 * i + fq * 4 + r;
            if (grow < NNODES) {
                unsigned short* orow = Wh + (size_t)grow * 256 + wn + fm;
#pragma unroll
                for (int j = 0; j < 8; ++j)
                    orow[16 * j] = f2bf(acc[i][j][r]);
            }
        }
    }
}

// ---------------- exclusive scan of counts -> row_start ----------------
__global__ __launch_bounds__(256) void k_scan1(const int* __restrict__ counts,
                                               int* __restrict__ row_start,
                                               int* __restrict__ blockSums) {
    __shared__ int ssum[256];
    const int tid = threadIdx.x;
    const int base = blockIdx.x * 1024 + tid * 4;
    int v[4];
#pragma unroll
    for (int c = 0; c < 4; ++c) v[c] = (base + c < NNODES) ? counts[base + c] : 0;
    const int s = v[0] + v[1] + v[2] + v[3];
    ssum[tid] = s;
    __syncthreads();
    for (int off = 1; off < 256; off <<= 1) {
        const int t = (tid >= off) ? ssum[tid - off] : 0;
        __syncthreads();
        ssum[tid] += t;
        __syncthreads();
    }
    if (tid == 255) blockSums[blockIdx.x] = ssum[255];
    int p = ssum[tid] - s;
#pragma unroll
    for (int c = 0; c < 4; ++c) {
        if (base + c < NNODES) row_start[base + c] = p;
        p += v[c];
    }
}

__global__ __launch_bounds__(256) void k_scan2(int* __restrict__ blockSums, int nb) {
    __shared__ int ssum[256];
    const int tid = threadIdx.x;
    const int s = (tid < nb) ? blockSums[tid] : 0;
    ssum[tid] = s;
    __syncthreads();
    for (int off = 1; off < 256; off <<= 1) {
        const int t = (tid >= off) ? ssum[tid - off] : 0;
        __syncthreads();
        ssum[tid] += t;
        __syncthreads();
    }
    if (tid < nb) blockSums[tid] = ssum[tid] - s;
}

__global__ void k_scan3(int* __restrict__ row_start, const int* __restrict__ blockSums) {
    const int i = blockIdx.x * blockDim.x + threadIdx.x;
    if (i < NNODES) row_start[i] += blockSums[i >> 10];
}

// ---------------- fused attention + scatter: 4 lanes/edge ----------------
// slot via atomicSub on counts (fills row backward; counts is consumed here)
__global__ __launch_bounds__(256) void k_attn_scatter(const float* __restrict__ label,
                                                      const int* __restrict__ src,
                                                      const int* __restrict__ dst,
                                                      const int* __restrict__ row_start,
                                                      int* __restrict__ counts,
                                                      uint2* __restrict__ sorted_pack) {
    const int t = blockIdx.x * 256 + threadIdx.x;
    const int e = t >> 2;
    const int l4 = t & 3;
    if (e >= NEDGES) return;
    const int s = src[e], d = dst[e];
    const float4* ls = (const float4*)&label[s * 32 + l4 * 8];
    const float4* ld = (const float4*)&label[d * 32 + l4 * 8];
    const float4 a0 = ls[0], a1 = ls[1];
    const float4 b0 = ld[0], b1 = ld[1];
    float dot = a0.x * b0.x + a0.y * b0.y + a0.z * b0.z + a0.w * b0.w
              + a1.x * b1.x + a1.y * b1.y + a1.z * b1.z + a1.w * b1.w;
    dot += __shfl_xor(dot, 1);
    dot += __shfl_xor(dot, 2);
    if (l4 == 0) {
        const float lr = dot >= 0.f ? dot : ALPHA * dot;
        const float ex = expf(lr);
        const int pos = row_start[s] + atomicSub(&counts[s], 1) - 1;
        sorted_pack[pos] = make_uint2((unsigned)d, __float_as_uint(ex));
    }
}

// ---------------- aggregation: 32 lanes/node, 16B gathers, x8 unroll ----------------
__global__ __launch_bounds__(256) void k_aggregate(const unsigned short* __restrict__ Wh,
                                                   const int* __restrict__ row_start,
                                                   const uint2* __restrict__ sorted_pack,
                                                   float* __restrict__ out) {
    const int node = blockIdx.x * 8 + (threadIdx.x >> 5);
    if (node >= NNODES) return;
    const int sub = threadIdx.x & 31;      // owns channels [sub*8, sub*8+8)
    const int rs = row_start[node];
    const int re = (node == NNODES - 1) ? NEDGES : row_start[node + 1];
    const unsigned short* __restrict__ Whc = Wh + sub * 8;
    float acc[8] = {0.f, 0.f, 0.f, 0.f, 0.f, 0.f, 0.f, 0.f};
    float wsum = 0.f;
    int i = rs;
    for (; i + 8 <= re; i += 8) {
        uint2 p[8];
        u16x8 v[8];
#pragma unroll
        for (int u = 0; u < 8; ++u) p[u] = sorted_pack[i + u];
#pragma unroll
        for (int u = 0; u < 8; ++u) v[u] = *(const u16x8*)&Whc[(size_t)p[u].x * 256];
#pragma unroll
        for (int u = 0; u < 8; ++u) {
            const float w = __uint_as_float(p[u].y);
            wsum += w;
#pragma unroll
            for (int c = 0; c < 8; ++c) acc[c] = fmaf(w, bf2f(v[u][c]), acc[c]);
        }
    }
    for (; i + 4 <= re; i += 4) {
        uint2 p[4];
        u16x8 v[4];
#pragma unroll
        for (int u = 0; u < 4; ++u) p[u] = sorted_pack[i + u];
#pragma unroll
        for (int u = 0; u < 4; ++u) v[u] = *(const u16x8*)&Whc[(size_t)p[u].x * 256];
#pragma unroll
        for (int u = 0; u < 4; ++u) {
            const float w = __uint_as_float(p[u].y);
            wsum += w;
#pragma unroll
            for (int c = 0; c < 8; ++c) acc[c] = fmaf(w, bf2f(v[u][c]), acc[c]);
        }
    }
    for (; i < re; ++i) {
        const uint2 p = sorted_pack[i];
        const u16x8 v = *(const u16x8*)&Whc[(size_t)p.x * 256];
        const float w = __uint_as_float(p.y);
        wsum += w;
#pragma unroll
        for (int c = 0; c < 8; ++c) acc[c] = fmaf(w, bf2f(v[c]), acc[c]);
    }
    const float inv = 1.f / fmaxf(wsum, EPSV);
    float4 o0 = make_float4(acc[0] * inv, acc[1] * inv, acc[2] * inv, acc[3] * inv);
    float4 o1 = make_float4(acc[4] * inv, acc[5] * inv, acc[6] * inv, acc[7] * inv);
    float* orow = out + (size_t)node * 256 + sub * 8;
    *(float4*)(orow + 0) = o0;
    *(float4*)(orow + 4) = o1;
}

extern "C" void kernel_launch(void* const* d_in, const int* in_sizes, int n_in,
                              void* d_out, int out_size, void* d_ws, size_t ws_size,
                              hipStream_t stream) {
    const float* h     = (const float*)d_in[0];   // [N,256]
    const float* label = (const float*)d_in[1];   // [N,32]
    const float* W     = (const float*)d_in[2];   // [256,256]
    const int*   adj   = (const int*)d_in[3];     // [2,E]
    const int* src = adj;
    const int* dst = adj + NEDGES;
    float* out = (float*)d_out;

    // workspace layout (bytes, 16B-aligned offsets; no trailing backslash comments)
    char* ws = (char*)d_ws;
    unsigned short* Wh  = (unsigned short*)(ws + 0);          // N*256*2 = 51,200,000
    unsigned short* Wt  = (unsigned short*)(ws + 51200000);   // 256*256*2
    uint2* sorted_pack  = (uint2*)(ws + 51400064);            // E*8 = 12,800,000
    int*   counts       = (int*)  (ws + 64200064);            // N*4
    int*   row_start    = (int*)  (ws + 64600064);            // N*4
    int*   blockSums    = (int*)  (ws + 65000064);            // 1024*4

    k_zero_prep<<<(NNODES + 255) / 256, 256, 0, stream>>>(counts, W, Wt);
    k_count<<<(NEDGES + 255) / 256, 256, 0, stream>>>(src, counts);

    const int nb = (NNODES + 1023) / 1024;  // 98
    k_scan1<<<nb, 256, 0, stream>>>(counts, row_start, blockSums);
    k_scan2<<<1, 256, 0, stream>>>(blockSums, nb);
    k_scan3<<<(NNODES + 255) / 256, 256, 0, stream>>>(row_start, blockSums);

    k_gemm<<<(NNODES + BM - 1) / BM, 256, 0, stream>>>(h, Wt, Wh);

    k_attn_scatter<<<(4 * NEDGES + 255) / 256, 256, 0, stream>>>(label, src, dst,
                                                                 row_start, counts, sorted_pack);
    k_aggregate<<<(NNODES + 7) / 8, 256, 0, stream>>>(Wh, row_start, sorted_pack, out);
}